// Round 2
// baseline (786.677 us; speedup 1.0000x reference)
//
#include <hip/hip_runtime.h>

typedef unsigned int u32;

#define FLT_BIG 3.402823466e+38f

// Order-preserving map: float -> u32 so unsigned atomicMin == float min.
__device__ __forceinline__ u32 f2ord(float f){
    u32 b = __float_as_uint(f);
    return (b & 0x80000000u) ? ~b : (b | 0x80000000u);
}
__device__ __forceinline__ float ord2f(u32 k){
    u32 b = (k & 0x80000000u) ? (k ^ 0x80000000u) : ~k;
    return __uint_as_float(b);
}

// Re-init min slots (ws is poisoned 0xAA every call) + write tail outputs
// (nbins as floats, bin_width). NOTE: JAX x64 is disabled -> "int64" inputs
// are actually int32 on device.
__global__ void k_init(u32* __restrict__ mins,
                       float* __restrict__ out_tail,
                       const int* __restrict__ nbins,
                       const float* __restrict__ bin_width,
                       int ndims){
    int t = threadIdx.x;
    if (t < 3) mins[t] = 0xFFFFFFFFu;
    if (t < ndims) out_tail[t] = (float)nbins[t];
    if (t == 0) out_tail[ndims] = bin_width[0];
}

// Per-dim min over [N,3] f32, read as groups of 3 float4 (= 4 points).
// Component->dim mapping is static per vector: v0:(0,1,2,0) v1:(1,2,0,1) v2:(2,0,1,2).
__global__ void k_min3(const float4* __restrict__ c4, int ngroups, u32* __restrict__ mins){
    float m0 = FLT_BIG, m1 = FLT_BIG, m2 = FLT_BIG;
    const int stride = gridDim.x * blockDim.x;
    for (int g = blockIdx.x * blockDim.x + threadIdx.x; g < ngroups; g += stride){
        const float4 v0 = c4[3*g+0];
        const float4 v1 = c4[3*g+1];
        const float4 v2 = c4[3*g+2];
        m0 = fminf(m0, fminf(v0.x, v0.w)); m1 = fminf(m1, v0.y); m2 = fminf(m2, v0.z);
        m1 = fminf(m1, fminf(v1.x, v1.w)); m2 = fminf(m2, v1.y); m0 = fminf(m0, v1.z);
        m2 = fminf(m2, fminf(v2.x, v2.w)); m0 = fminf(m0, v2.y); m1 = fminf(m1, v2.z);
    }
    #pragma unroll
    for (int off = 32; off > 0; off >>= 1){
        m0 = fminf(m0, __shfl_down(m0, off));
        m1 = fminf(m1, __shfl_down(m1, off));
        m2 = fminf(m2, __shfl_down(m2, off));
    }
    if ((threadIdx.x & 63) == 0){
        atomicMin(mins + 0, f2ord(m0));
        atomicMin(mins + 1, f2ord(m1));
        atomicMin(mins + 2, f2ord(m2));
    }
}

__device__ __forceinline__ int bin_of(float x, float mn, float w, int nb){
    // match np/jnp exactly: float32 sub, IEEE float32 div, floor, clip
    float c = x - mn;
    int b = (int)floorf(c / w);
    b = b < 0 ? 0 : b;
    b = b > nb - 1 ? nb - 1 : b;
    return b;
}

__global__ void k_bin(const float* __restrict__ coords,
                      const int* __restrict__ row_splits, int n_rs,
                      const int* __restrict__ nbins,
                      const float* __restrict__ bin_width,
                      const u32* __restrict__ mins,
                      int N,
                      float* __restrict__ out,
                      int* __restrict__ counts){
    const float w  = bin_width[0];
    const float mn0 = ord2f(mins[0]);
    const float mn1 = ord2f(mins[1]);
    const float mn2 = ord2f(mins[2]);
    const int nb0 = nbins[0], nb1 = nbins[1], nb2 = nbins[2];

    // Preload interior splits (indices 1..n_rs) into registers, static-indexed.
    int sp[8];
    #pragma unroll
    for (int k = 0; k < 8; ++k){
        int idx = k + 1;
        sp[k] = (idx <= n_rs) ? row_splits[idx] : 0x7FFFFFFF;
    }

    float4* out_assigned = (float4*)out;                 // [N] x float4
    float*  out_flat     = out + 4LL * (long long)N;     // [N]
    const float4* c4 = (const float4*)coords;

    const int ngroups = N >> 2;
    const int stride = gridDim.x * blockDim.x;
    const int tid0 = blockIdx.x * blockDim.x + threadIdx.x;

    for (int g = tid0; g < ngroups; g += stride){
        const float4 v0 = c4[3*g+0];
        const float4 v1 = c4[3*g+1];
        const float4 v2 = c4[3*g+2];
        float px[4], py[4], pz[4];
        px[0]=v0.x; py[0]=v0.y; pz[0]=v0.z;
        px[1]=v0.w; py[1]=v1.x; pz[1]=v1.y;
        px[2]=v1.z; py[2]=v1.w; pz[2]=v2.x;
        px[3]=v2.y; py[3]=v2.z; pz[3]=v2.w;

        const int base = g << 2;
        float fl[4];
        #pragma unroll
        for (int j = 0; j < 4; ++j){
            const int p = base + j;
            int r = 0;
            #pragma unroll
            for (int k = 0; k < 8; ++k) r += (p >= sp[k]) ? 1 : 0;
            if (n_rs > 8){
                for (int k = 9; k <= n_rs; ++k) r += (p >= row_splits[k]) ? 1 : 0;
            }
            const int b0 = bin_of(px[j], mn0, w, nb0);
            const int b1 = bin_of(py[j], mn1, w, nb1);
            const int b2 = bin_of(pz[j], mn2, w, nb2);
            out_assigned[p] = make_float4((float)r, (float)b0, (float)b1, (float)b2);
            const int flat = ((r * nb0 + b0) * nb1 + b1) * nb2 + b2;
            fl[j] = (float)flat;
            atomicAdd(counts + flat, 1);
        }
        *(float4*)(out_flat + base) = make_float4(fl[0], fl[1], fl[2], fl[3]);
    }

    // Tail points (N % 4 != 0) — scalar path, first `rem` threads.
    const int rem = N - (ngroups << 2);
    if (tid0 < rem){
        const int p = (ngroups << 2) + tid0;
        const float x = coords[3LL*p+0];
        const float y = coords[3LL*p+1];
        const float z = coords[3LL*p+2];
        int r = 0;
        #pragma unroll
        for (int k = 0; k < 8; ++k) r += (p >= sp[k]) ? 1 : 0;
        if (n_rs > 8){
            for (int k = 9; k <= n_rs; ++k) r += (p >= row_splits[k]) ? 1 : 0;
        }
        const int b0 = bin_of(x, mn0, w, nb0);
        const int b1 = bin_of(y, mn1, w, nb1);
        const int b2 = bin_of(z, mn2, w, nb2);
        out_assigned[p] = make_float4((float)r, (float)b0, (float)b1, (float)b2);
        const int flat = ((r * nb0 + b0) * nb1 + b1) * nb2 + b2;
        out_flat[p] = (float)flat;
        atomicAdd(counts + flat, 1);
    }
}

// In-place: reinterpret accumulated int32 counts as float32 values.
__global__ void k_convert(float* __restrict__ buf, int n){
    int i = blockIdx.x * blockDim.x + threadIdx.x;
    if (i < n){
        int v = ((const int*)buf)[i];
        buf[i] = (float)v;
    }
}

extern "C" void kernel_launch(void* const* d_in, const int* in_sizes, int n_in,
                              void* d_out, int out_size, void* d_ws, size_t ws_size,
                              hipStream_t stream){
    const float* coords    = (const float*)d_in[0];
    const int*  row_splits = (const int*)d_in[1];   // JAX x64 off: int32!
    const float* bin_width = (const float*)d_in[2];
    const int*  nbins      = (const int*)d_in[3];   // int32!

    const int N     = in_sizes[0] / 3;      // 8,000,000
    const int n_rs  = in_sizes[1] - 1;      // 4 events
    const int ndims = in_sizes[3];          // 3
    const long long total_bins = (long long)out_size - 5LL * N - ndims - 1;

    float* out        = (float*)d_out;
    float* out_counts = out + 5LL * N;           // [total_bins]
    float* out_tail   = out_counts + total_bins; // nbins (ndims) + bin_width (1)
    u32*   mins       = (u32*)d_ws;              // 3 slots
    int*   counts     = (int*)out_counts;        // accumulate in-place as int

    hipMemsetAsync(out_counts, 0, (size_t)total_bins * sizeof(int), stream);
    k_init<<<1, 64, 0, stream>>>(mins, out_tail, nbins, bin_width, ndims);

    const int ngroups = N >> 2;
    int gmin = (ngroups + 255) / 256; if (gmin > 2048) gmin = 2048;
    k_min3<<<gmin, 256, 0, stream>>>((const float4*)coords, ngroups, mins);

    int gbin = (ngroups + 255) / 256; if (gbin > 2048) gbin = 2048;
    k_bin<<<gbin, 256, 0, stream>>>(coords, row_splits, n_rs, nbins, bin_width,
                                    mins, N, out, counts);

    int gcv = (int)((total_bins + 255) / 256);
    k_convert<<<gcv, 256, 0, stream>>>(out_counts, (int)total_bins);
}

// Round 4
// 784.549 us; speedup vs baseline: 1.0027x; 1.0027x over previous
//
#include <hip/hip_runtime.h>

typedef unsigned int u32;

#define FLT_BIG 3.402823466e+38f
#define NXCD 8

// Order-preserving map: float -> u32 so unsigned atomicMin == float min.
__device__ __forceinline__ u32 f2ord(float f){
    u32 b = __float_as_uint(f);
    return (b & 0x80000000u) ? ~b : (b | 0x80000000u);
}
__device__ __forceinline__ float ord2f(u32 k){
    u32 b = (k & 0x80000000u) ? (k ^ 0x80000000u) : ~k;
    return __uint_as_float(b);
}

// HW_REG_XCC_ID = 20, size 4 -> simm16 = 20 | ((4-1)<<11)
__device__ __forceinline__ int xcc_id(){
    return (int)(__builtin_amdgcn_s_getreg(20 | (3 << 11)) & 7u);
}

// Re-init min slots (ws is poisoned 0xAA every call) + write tail outputs
// (nbins as floats, bin_width). NOTE: JAX x64 disabled -> "int64" inputs are int32.
__global__ void k_init(u32* __restrict__ mins,
                       float* __restrict__ out_tail,
                       const int* __restrict__ nbins,
                       const float* __restrict__ bin_width,
                       int ndims){
    int t = threadIdx.x;
    if (t < 3) mins[t] = 0xFFFFFFFFu;
    if (t < ndims) out_tail[t] = (float)nbins[t];
    if (t == 0) out_tail[ndims] = bin_width[0];
}

// Per-dim min over [N,3] f32, read as groups of 3 float4 (= 4 points).
__global__ void k_min3(const float4* __restrict__ c4, int ngroups, u32* __restrict__ mins){
    float m0 = FLT_BIG, m1 = FLT_BIG, m2 = FLT_BIG;
    const int stride = gridDim.x * blockDim.x;
    for (int g = blockIdx.x * blockDim.x + threadIdx.x; g < ngroups; g += stride){
        const float4 v0 = c4[3*g+0];
        const float4 v1 = c4[3*g+1];
        const float4 v2 = c4[3*g+2];
        m0 = fminf(m0, fminf(v0.x, v0.w)); m1 = fminf(m1, v0.y); m2 = fminf(m2, v0.z);
        m1 = fminf(m1, fminf(v1.x, v1.w)); m2 = fminf(m2, v1.y); m0 = fminf(m0, v1.z);
        m2 = fminf(m2, fminf(v2.x, v2.w)); m0 = fminf(m0, v2.y); m1 = fminf(m1, v2.z);
    }
    #pragma unroll
    for (int off = 32; off > 0; off >>= 1){
        m0 = fminf(m0, __shfl_down(m0, off));
        m1 = fminf(m1, __shfl_down(m1, off));
        m2 = fminf(m2, __shfl_down(m2, off));
    }
    if ((threadIdx.x & 63) == 0){
        atomicMin(mins + 0, f2ord(m0));
        atomicMin(mins + 1, f2ord(m1));
        atomicMin(mins + 2, f2ord(m2));
    }
}

__device__ __forceinline__ int bin_of(float x, float mn, float w, int nb){
    float c = x - mn;
    int b = (int)floorf(c / w);
    b = b < 0 ? 0 : b;
    b = b > nb - 1 ? nb - 1 : b;
    return b;
}

// USE_PART=1: increment XCD-private partial histogram with workgroup-scope
// atomics (plain global_atomic_add, executes in the local XCD's L2, stays
// cached). Each copy is touched by exactly one XCD -> atomicity at that L2
// is sufficient; kernel-boundary flush publishes to the reduce kernel.
template<int USE_PART>
__global__ void k_bin(const float* __restrict__ coords,
                      const int* __restrict__ row_splits, int n_rs,
                      const int* __restrict__ nbins,
                      const float* __restrict__ bin_width,
                      const u32* __restrict__ mins,
                      int N,
                      float* __restrict__ out,
                      int* __restrict__ counts,   // partials base (USE_PART) or out counts
                      int total_bins){
    const float w  = bin_width[0];
    const float mn0 = ord2f(mins[0]);
    const float mn1 = ord2f(mins[1]);
    const float mn2 = ord2f(mins[2]);
    const int nb0 = nbins[0], nb1 = nbins[1], nb2 = nbins[2];

    int* my_counts = counts;
    if (USE_PART) my_counts = counts + (long long)xcc_id() * total_bins;

    int sp[8];
    #pragma unroll
    for (int k = 0; k < 8; ++k){
        int idx = k + 1;
        sp[k] = (idx <= n_rs) ? row_splits[idx] : 0x7FFFFFFF;
    }

    float4* out_assigned = (float4*)out;                 // [N] x float4
    float*  out_flat     = out + 4LL * (long long)N;     // [N]
    const float4* c4 = (const float4*)coords;

    const int ngroups = N >> 2;
    const int stride = gridDim.x * blockDim.x;
    const int tid0 = blockIdx.x * blockDim.x + threadIdx.x;

    for (int g = tid0; g < ngroups; g += stride){
        const float4 v0 = c4[3*g+0];
        const float4 v1 = c4[3*g+1];
        const float4 v2 = c4[3*g+2];
        float px[4], py[4], pz[4];
        px[0]=v0.x; py[0]=v0.y; pz[0]=v0.z;
        px[1]=v0.w; py[1]=v1.x; pz[1]=v1.y;
        px[2]=v1.z; py[2]=v1.w; pz[2]=v2.x;
        px[3]=v2.y; py[3]=v2.z; pz[3]=v2.w;

        const int base = g << 2;
        float fl[4];
        #pragma unroll
        for (int j = 0; j < 4; ++j){
            const int p = base + j;
            int r = 0;
            #pragma unroll
            for (int k = 0; k < 8; ++k) r += (p >= sp[k]) ? 1 : 0;
            if (n_rs > 8){
                for (int k = 9; k <= n_rs; ++k) r += (p >= row_splits[k]) ? 1 : 0;
            }
            const int b0 = bin_of(px[j], mn0, w, nb0);
            const int b1 = bin_of(py[j], mn1, w, nb1);
            const int b2 = bin_of(pz[j], mn2, w, nb2);
            out_assigned[p] = make_float4((float)r, (float)b0, (float)b1, (float)b2);
            const int flat = ((r * nb0 + b0) * nb1 + b1) * nb2 + b2;
            fl[j] = (float)flat;
            if (USE_PART){
                __hip_atomic_fetch_add(my_counts + flat, 1, __ATOMIC_RELAXED,
                                       __HIP_MEMORY_SCOPE_WORKGROUP);
            } else {
                atomicAdd(my_counts + flat, 1);
            }
        }
        *(float4*)(out_flat + base) = make_float4(fl[0], fl[1], fl[2], fl[3]);
    }

    // Tail points (N % 4 != 0)
    const int rem = N - (ngroups << 2);
    if (tid0 < rem){
        const int p = (ngroups << 2) + tid0;
        const float x = coords[3LL*p+0];
        const float y = coords[3LL*p+1];
        const float z = coords[3LL*p+2];
        int r = 0;
        #pragma unroll
        for (int k = 0; k < 8; ++k) r += (p >= sp[k]) ? 1 : 0;
        if (n_rs > 8){
            for (int k = 9; k <= n_rs; ++k) r += (p >= row_splits[k]) ? 1 : 0;
        }
        const int b0 = bin_of(x, mn0, w, nb0);
        const int b1 = bin_of(y, mn1, w, nb1);
        const int b2 = bin_of(z, mn2, w, nb2);
        out_assigned[p] = make_float4((float)r, (float)b0, (float)b1, (float)b2);
        const int flat = ((r * nb0 + b0) * nb1 + b1) * nb2 + b2;
        out_flat[p] = (float)flat;
        if (USE_PART){
            __hip_atomic_fetch_add(my_counts + flat, 1, __ATOMIC_RELAXED,
                                   __HIP_MEMORY_SCOPE_WORKGROUP);
        } else {
            atomicAdd(my_counts + flat, 1);
        }
    }
}

// counts_out[b] = (float) sum over 8 XCD partials. Also covers the convert.
__global__ void k_reduce(const int* __restrict__ part, int total_bins,
                         float* __restrict__ counts_out){
    int b = blockIdx.x * blockDim.x + threadIdx.x;
    if (b < total_bins){
        int s = 0;
        #pragma unroll
        for (int x = 0; x < NXCD; ++x) s += part[(long long)x * total_bins + b];
        counts_out[b] = (float)s;
    }
}

// Fallback path: reinterpret accumulated int32 counts as float32 values.
__global__ void k_convert(float* __restrict__ buf, int n){
    int i = blockIdx.x * blockDim.x + threadIdx.x;
    if (i < n){
        int v = ((const int*)buf)[i];
        buf[i] = (float)v;
    }
}

extern "C" void kernel_launch(void* const* d_in, const int* in_sizes, int n_in,
                              void* d_out, int out_size, void* d_ws, size_t ws_size,
                              hipStream_t stream){
    const float* coords    = (const float*)d_in[0];
    const int*  row_splits = (const int*)d_in[1];   // JAX x64 off: int32
    const float* bin_width = (const float*)d_in[2];
    const int*  nbins      = (const int*)d_in[3];   // int32

    const int N     = in_sizes[0] / 3;      // 8,000,000
    const int n_rs  = in_sizes[1] - 1;      // 4 events
    const int ndims = in_sizes[3];          // 3
    const long long total_bins = (long long)out_size - 5LL * N - ndims - 1;

    float* out        = (float*)d_out;
    float* out_counts = out + 5LL * N;           // [total_bins]
    float* out_tail   = out_counts + total_bins; // nbins (ndims) + bin_width (1)
    u32*   mins       = (u32*)d_ws;              // 3 slots
    int*   part       = (int*)((char*)d_ws + 256);

    const size_t need = 256 + (size_t)NXCD * (size_t)total_bins * sizeof(int);
    const bool use_part = (ws_size >= need);

    k_init<<<1, 64, 0, stream>>>(mins, out_tail, nbins, bin_width, ndims);

    const int ngroups = N >> 2;
    int gmin = (ngroups + 255) / 256; if (gmin > 2048) gmin = 2048;
    k_min3<<<gmin, 256, 0, stream>>>((const float4*)coords, ngroups, mins);

    int gbin = (ngroups + 255) / 256; if (gbin > 2048) gbin = 2048;

    if (use_part){
        hipMemsetAsync(part, 0, (size_t)NXCD * (size_t)total_bins * sizeof(int), stream);
        k_bin<1><<<gbin, 256, 0, stream>>>(coords, row_splits, n_rs, nbins, bin_width,
                                           mins, N, out, part, (int)total_bins);
        int grd = (int)((total_bins + 255) / 256);
        k_reduce<<<grd, 256, 0, stream>>>(part, (int)total_bins, out_counts);
    } else {
        hipMemsetAsync(out_counts, 0, (size_t)total_bins * sizeof(int), stream);
        k_bin<0><<<gbin, 256, 0, stream>>>(coords, row_splits, n_rs, nbins, bin_width,
                                           mins, N, out, (int*)out_counts, (int)total_bins);
        int gcv = (int)((total_bins + 255) / 256);
        k_convert<<<gcv, 256, 0, stream>>>(out_counts, (int)total_bins);
    }
}